// Round 7
// baseline (187.640 us; speedup 1.0000x reference)
//
#include <hip/hip_runtime.h>
#include <hip/hip_bf16.h>
#include <math.h>

#define BATCH 16384
#define NSETS 1024
#define ALPHA 0.001f
#define BETA  0.001f

// MFMA GEMM tile: 128x128 block, BK=64, 256 threads (4 waves, 2x2 wave grid,
// each wave 64x64 = 4x4 grid of 16x16x32 bf16 MFMA tiles, 2 k-steps per iter)
#define BM 128
#define BN 128
#define BK 64
#define NSTRIPE (BATCH / BM)            // 128 m-stripes
#define NBLK_N  (NSETS / BN)            // 8 n-blocks per stripe
#define GEMM_BLOCKS (NSTRIPE * NBLK_N)  // 1024
#define KITER (NSETS / BK)              // 16

#define MAGIC 0x5EEDF00Du

typedef __attribute__((ext_vector_type(4))) float f32x4;
typedef __attribute__((ext_vector_type(8))) __bf16 bf16x8;

// ws float-index layout (all cells rewritten every launch; flags use MAGIC
// which differs from the 0xAAAAAAAA poison):
//   [0 .. 1024)          per-block flags (uint)
//   [1024 .. 2048)       per-block mr partials
//   [2048 .. 3072)       per-block bce partials
//   [4096 .. 135168)     row-sum slices [stripe][nblk][128] (write-once)
//   [135168 .. 135296)   per-stripe ms partials
//   [135296 .. 135424)   per-stripe flags (uint)
#define F_TFLAG 0
#define F_MRP   1024
#define F_BCEP  2048
#define F_ROWS  4096
#define F_SMS   135168
#define F_SFLAG 135296

__device__ __forceinline__ void coh_store(float* p, float v) {
    __hip_atomic_store(p, v, __ATOMIC_RELAXED, __HIP_MEMORY_SCOPE_AGENT);
}
__device__ __forceinline__ float coh_load(const float* p) {
    return __hip_atomic_load(p, __ATOMIC_RELAXED, __HIP_MEMORY_SCOPE_AGENT);
}
__device__ __forceinline__ void coh_store_u(unsigned* p, unsigned v) {
    __hip_atomic_store(p, v, __ATOMIC_RELAXED, __HIP_MEMORY_SCOPE_AGENT);
}
__device__ __forceinline__ unsigned coh_load_u(const unsigned* p) {
    return __hip_atomic_load(p, __ATOMIC_RELAXED, __HIP_MEMORY_SCOPE_AGENT);
}

__device__ __forceinline__ float block_reduce_sum(float v, float* sm) {
    #pragma unroll
    for (int off = 32; off > 0; off >>= 1) v += __shfl_down(v, off, 64);
    const int lane = threadIdx.x & 63;
    const int wid  = threadIdx.x >> 6;
    if (lane == 0) sm[wid] = v;
    __syncthreads();
    const int nw = blockDim.x >> 6;
    v = (threadIdx.x < nw) ? sm[threadIdx.x] : 0.0f;
    if (wid == 0) {
        #pragma unroll
        for (int off = 32; off > 0; off >>= 1) v += __shfl_down(v, off, 64);
    }
    return v;  // valid in thread 0
}

// fp32x4 -> 4 bf16 (RNE) -> 8B LDS write
__device__ __forceinline__ void cvt_store8(void* lp, float4 v) {
    __hip_bfloat162 lo = __float22bfloat162_rn(make_float2(v.x, v.y));
    __hip_bfloat162 hi = __float22bfloat162_rn(make_float2(v.z, v.w));
    uint2 u;
    u.x = *(unsigned*)&lo;
    u.y = *(unsigned*)&hi;
    *(uint2*)lp = u;   // ds_write_b64
}

// ---- single fused kernel: GEMM (+in-loop fp32->bf16), BCE, all reductions ----
// XCD swizzle: block i -> XCD i%8 (CP round-robin); all 8 n-blocks of an
// m-stripe on ONE XCD so the fp32 A-panel is fetched into its L2 once.
// LDS layout: 16B slot (row r, k8) at 8*r + (k8 ^ (r&7))  [conflict-free,
// validated R3..R6]; staging is reg->cvt->ds_write so next-tile global loads
// overlap current-tile MFMA (no vmcnt(0)-drain barrier on the load path).
__global__ __launch_bounds__(256)
void mega_kernel(const float* __restrict__ A,     // pred fp32 [BATCH, NSETS]
                 const float* __restrict__ Bm,    // moebius fp32 [NSETS, NSETS]
                 const float* __restrict__ membership,
                 const int*   __restrict__ tidx,
                 float* __restrict__ ws,
                 float* __restrict__ out) {
    __shared__ __align__(16) unsigned short Alds[BM * BK];  // 16 KB
    __shared__ __align__(16) unsigned short Blds[BN * BK];  // 16 KB
    __shared__ float rowacc[BM];
    __shared__ float sm[4];

    const int tid  = threadIdx.x;
    const int lane = tid & 63;
    const int w    = tid >> 6;
    const int wm   = w >> 1;
    const int wn   = w & 1;
    const int lr   = lane & 15;
    const int q    = lane >> 4;

    const int id     = blockIdx.x;
    const int xcd    = id & 7;
    const int slot   = id >> 3;                 // 0..127 within XCD
    const int grp    = slot >> 3;               // 0..15
    const int stripe = xcd * 16 + grp;
    const int nblk   = slot & 7;
    const int m0     = stripe * BM;
    const int n0     = nblk * BN;

    if (tid < BM) rowacc[tid] = 0.0f;

    f32x4 acc[4][4];
    #pragma unroll
    for (int i = 0; i < 4; i++)
        #pragma unroll
        for (int j = 0; j < 4; j++) acc[i][j] = (f32x4){0.f, 0.f, 0.f, 0.f};

    // staging map: float4 index f = tid + j*256 -> row r = f>>4, k4 = tid&15
    // LDS byte offset: slot(r, k8=k4>>1) * 16 + (k4&1)*8
    const int k4 = tid & 15;
    size_t ga[8], gb[8];
    unsigned lo[8];
    #pragma unroll
    for (int j = 0; j < 8; j++) {
        const int r = (tid >> 4) + j * 16;
        ga[j] = (size_t)(m0 + r) * NSETS + k4 * 4;
        gb[j] = (size_t)(n0 + r) * NSETS + k4 * 4;
        lo[j] = (unsigned)((8 * r + ((k4 >> 1) ^ (r & 7))) * 16 + (k4 & 1) * 8);
    }
    const int sw = lr & 7;  // fragment-read swizzle term

    // prologue: stage tile 0
    {
        float4 pa[8], pb[8];
        #pragma unroll
        for (int j = 0; j < 8; j++) {
            pa[j] = *(const float4*)(A  + ga[j]);
            pb[j] = *(const float4*)(Bm + gb[j]);
        }
        #pragma unroll
        for (int j = 0; j < 8; j++) {
            cvt_store8((char*)Alds + lo[j], pa[j]);
            cvt_store8((char*)Blds + lo[j], pb[j]);
        }
        __syncthreads();
    }

    for (int it = 0; it < KITER; it++) {
        // prefetch next tile's fp32 into registers (overlaps the MFMAs below)
        float4 pa[8], pb[8];
        if (it + 1 < KITER) {
            const int nk = (it + 1) * BK;
            #pragma unroll
            for (int j = 0; j < 8; j++) {
                pa[j] = *(const float4*)(A  + ga[j] + nk);
                pb[j] = *(const float4*)(Bm + gb[j] + nk);
            }
        }
        // compute on current LDS tile
        #pragma unroll
        for (int h = 0; h < 2; h++) {
            bf16x8 a[4], b[4];
            const int hq = h * 4 + q;
            #pragma unroll
            for (int mi = 0; mi < 4; mi++)
                a[mi] = *(const bf16x8*)&Alds[(wm * 64 + mi * 16 + lr) * BK + 8 * (hq ^ sw)];
            #pragma unroll
            for (int ni = 0; ni < 4; ni++)
                b[ni] = *(const bf16x8*)&Blds[(wn * 64 + ni * 16 + lr) * BK + 8 * (hq ^ sw)];
            #pragma unroll
            for (int mi = 0; mi < 4; mi++)
                #pragma unroll
                for (int ni = 0; ni < 4; ni++)
                    acc[mi][ni] = __builtin_amdgcn_mfma_f32_16x16x32_bf16(
                        a[mi], b[ni], acc[mi][ni], 0, 0, 0);
        }
        __syncthreads();
        if (it + 1 < KITER) {
            #pragma unroll
            for (int j = 0; j < 8; j++) {
                cvt_store8((char*)Alds + lo[j], pa[j]);
                cvt_store8((char*)Blds + lo[j], pb[j]);
            }
        }
        __syncthreads();
    }

    // ---- GEMM epilogue: mr partial + per-row sums (C/D: col=lane&15, row=q*4+r)
    float mrpart = 0.0f;
    float rs[4][4];
    #pragma unroll
    for (int mi = 0; mi < 4; mi++)
        #pragma unroll
        for (int r = 0; r < 4; r++) rs[mi][r] = 0.0f;
    #pragma unroll
    for (int mi = 0; mi < 4; mi++)
        #pragma unroll
        for (int ni = 0; ni < 4; ni++)
            #pragma unroll
            for (int r = 0; r < 4; r++) {
                const float m = acc[mi][ni][r];
                mrpart    += fmaxf(-m, 0.0f);
                rs[mi][r] += m;
            }
    #pragma unroll
    for (int mi = 0; mi < 4; mi++)
        #pragma unroll
        for (int r = 0; r < 4; r++) {
            float v = rs[mi][r];
            #pragma unroll
            for (int off = 1; off < 16; off <<= 1) v += __shfl_xor(v, off, 16);
            if (lr == 0)
                atomicAdd(&rowacc[wm * 64 + mi * 16 + q * 4 + r], v);
        }
    const float mrtot = block_reduce_sum(mrpart, sm);  // has a barrier inside
    __syncthreads();   // rowacc complete

    // write-once partials at the coherent point (no zero-init needed)
    if (tid < BM)  coh_store(&ws[F_ROWS + (stripe * 8 + nblk) * BM + tid], rowacc[tid]);
    if (tid == 0)  coh_store(&ws[F_MRP + id], mrtot);

    // ---- BCE phase: this block's 1/1024 chunk of pred (L3-hot by now) ----
    {
        const float eps = 1e-7f;
        const float hi  = 1.0f - 1e-7f;
        float accb = 0.0f;
        const int base = id * 4096 + tid;     // float4 index
        #pragma unroll
        for (int k = 0; k < 16; k++) {
            const int i  = base + k * 256;
            const int b  = i >> 8;
            const int s4 = i & 255;
            const float4 p4 = ((const float4*)A)[i];
            const int cls   = tidx[b];
            const float4 t4 = ((const float4*)membership)[(cls << 8) + s4];
            const float ps[4] = {p4.x, p4.y, p4.z, p4.w};
            const float ts[4] = {t4.x, t4.y, t4.z, t4.w};
            #pragma unroll
            for (int jj = 0; jj < 4; jj++) {
                const float cp = fminf(fmaxf(ps[jj], eps), hi);
                const float x  = (ts[jj] > 0.5f) ? cp : (1.0f - cp);
                accb += __logf(x);
            }
        }
        const float bcetot = block_reduce_sum(accb, sm);
        if (tid == 0) coh_store(&ws[F_BCEP + id], bcetot);
    }

    // ---- flag: all this block's partials are at the coherent point ----
    // (each wave's s_waitcnt vmcnt(0) before the barrier drains its stores)
    __syncthreads();
    if (tid == 0) coh_store_u((unsigned*)&ws[F_TFLAG + id], MAGIC);

    // ---- stripe waiter (nblk==7): reduce |rowsum-1| over its 128 rows ----
    if (nblk == 7) {
        if (tid < 7) {   // peers j=0..6 (same stripe); co-resident or retired
            const int peer = xcd + 8 * (8 * grp + tid);
            while (coh_load_u((const unsigned*)&ws[F_TFLAG + peer]) != MAGIC) {}
        }
        __syncthreads();
        float sms = 0.0f;
        if (tid < BM) {
            float s = 0.0f;
            #pragma unroll
            for (int j = 0; j < 8; j++)
                s += coh_load(&ws[F_ROWS + (stripe * 8 + j) * BM + tid]);
            sms = fabsf(s - 1.0f);
        }
        __syncthreads();                 // sm reuse guard
        const float mssum = block_reduce_sum(sms, sm);
        if (tid == 0) coh_store(&ws[F_SMS + stripe], mssum);
        __syncthreads();                 // drain the ms store
        if (tid == 0) coh_store_u((unsigned*)&ws[F_SFLAG + stripe], MAGIC);
    }

    // ---- global finalizer: block 1023 (stripe 127's waiter) ----
    if (id == GEMM_BLOCKS - 1) {
        if (tid < NSTRIPE)
            while (coh_load_u((const unsigned*)&ws[F_SFLAG + tid]) != MAGIC) {}
        __syncthreads();
        float sms = (tid < NSTRIPE) ? coh_load(&ws[F_SMS + tid]) : 0.0f;
        float smr = 0.0f, sbce = 0.0f;
        #pragma unroll
        for (int k = 0; k < 4; k++) {
            smr  += coh_load(&ws[F_MRP  + tid + k * 256]);
            sbce += coh_load(&ws[F_BCEP + tid + k * 256]);
        }
        __syncthreads();                 // sm reuse guard
        const float mssum = block_reduce_sum(sms, sm);
        __syncthreads();
        const float mrsum = block_reduce_sum(smr, sm);
        __syncthreads();
        const float bcesum = block_reduce_sum(sbce, sm);
        if (tid == 0) {
            const float inv = 1.0f / ((float)BATCH * (float)NSETS);
            const float bce = -bcesum * inv;
            const float mr  =  mrsum * inv;
            const float ms  =  mssum / (float)BATCH;
            out[0] = bce + ALPHA * mr + BETA * ms;
            out[1] = bce;
            out[2] = mr;
            out[3] = ms;
        }
    }
}

extern "C" void kernel_launch(void* const* d_in, const int* in_sizes, int n_in,
                              void* d_out, int out_size, void* d_ws, size_t ws_size,
                              hipStream_t stream) {
    const float* pred       = (const float*)d_in[0];
    const float* membership = (const float*)d_in[1];
    const float* moebius    = (const float*)d_in[2];
    const int*   tidx       = (const int*)d_in[3];
    float* out = (float*)d_out;
    float* ws  = (float*)d_ws;

    mega_kernel<<<GEMM_BLOCKS, 256, 0, stream>>>(
        pred, moebius, membership, tidx, ws, out);
}